// Round 1
// baseline (209.449 us; speedup 1.0000x reference)
//
#include <hip/hip_runtime.h>
#include <hip/hip_bf16.h>

#define S_TOK 8192
#define NEXP 64
#define MDIM 1024
#define CAP 128
#define NCH 512
#define CHUNK 16   // tokens per block
#define TPW 4      // tokens per wave

// flat output offsets (all fp32 elements)
#define OFF2 67108865    // dispatch_mask start  (1 + 8192*64*128)
#define OFF3 134217729   // mask1 start
#define OFF4 134742017   // exp_counts start
#define OFF5 134742081   // indices1_s start

__global__ __launch_bounds__(256) void gate_kernel(
    const float* __restrict__ x, const float* __restrict__ wg,
    int* __restrict__ ind, int* __restrict__ rnk, float* __restrict__ gval,
    int* __restrict__ counts, float* __restrict__ gparts)
{
  __shared__ float s_gsum[4][64];
  __shared__ int s_ind[CHUNK];
  const int b = blockIdx.x;
  const int lane = threadIdx.x & 63;   // expert
  const int wv = threadIdx.x >> 6;     // wave 0..3
  const int tok0 = b * CHUNK + wv * TPW;

  float acc[TPW] = {0.f, 0.f, 0.f, 0.f};
  for (int d = 0; d < MDIM; d += 4) {
    const float w0 = wg[(d + 0) * NEXP + lane];
    const float w1 = wg[(d + 1) * NEXP + lane];
    const float w2 = wg[(d + 2) * NEXP + lane];
    const float w3 = wg[(d + 3) * NEXP + lane];
#pragma unroll
    for (int t = 0; t < TPW; ++t) {
      const float4 xv = *reinterpret_cast<const float4*>(x + (tok0 + t) * MDIM + d);
      acc[t] = fmaf(xv.x, w0, acc[t]);
      acc[t] = fmaf(xv.y, w1, acc[t]);
      acc[t] = fmaf(xv.z, w2, acc[t]);
      acc[t] = fmaf(xv.w, w3, acc[t]);
    }
  }

  float colsum = 0.f;
#pragma unroll
  for (int t = 0; t < TPW; ++t) {
    const float logit = acc[t];
    float m = logit;
#pragma unroll
    for (int off = 32; off > 0; off >>= 1) m = fmaxf(m, __shfl_xor(m, off, 64));
    const float ex = __expf(logit - m);
    float sm = ex;
#pragma unroll
    for (int off = 32; off > 0; off >>= 1) sm += __shfl_xor(sm, off, 64);
    colsum += ex / sm;                 // this lane's gate for this token
    const unsigned long long bal = __ballot(logit == m);
    const int widx = (int)(__ffsll(bal) - 1);   // lowest lane with max == argmax tie-break
    if (lane == 0) {
      const int tk = tok0 + t;
      ind[tk] = widx;
      gval[tk] = 1.0f / sm;            // gate of winning expert = exp(0)/sum
      s_ind[wv * TPW + t] = widx;
    }
  }
  s_gsum[wv][lane] = colsum;
  __syncthreads();
  if (wv == 0) {
    const float g = s_gsum[0][lane] + s_gsum[1][lane] + s_gsum[2][lane] + s_gsum[3][lane];
    gparts[b * NEXP + lane] = g;
    // deterministic within-chunk rank (token order preserved)
    int cnt = 0;
#pragma unroll
    for (int t = 0; t < CHUNK; ++t) {
      const int e = s_ind[t];
      const int r = __shfl(cnt, e, 64);
      if (lane == 0) rnk[b * CHUNK + t] = r;
      cnt += (lane == e) ? 1 : 0;
    }
    counts[b * NEXP + lane] = cnt;
  }
}

__global__ void reduce_kernel(const int* __restrict__ counts, const float* __restrict__ gparts,
                              int* __restrict__ offs, float* __restrict__ out)
{
  const int e = threadIdx.x;  // 64 threads, lane = expert
  int running = 0;
  float gsum = 0.f;
#pragma unroll 8
  for (int ch = 0; ch < NCH; ++ch) {
    const int c = counts[ch * NEXP + e];
    const float gp = gparts[ch * NEXP + e];
    offs[ch * NEXP + e] = running;   // exclusive prefix per expert
    running += c;
    gsum += gp;
  }
  out[OFF4 + e] = (float)running;    // exp_counts
  const float me = gsum * (1.0f / (float)S_TOK);
  const float ce = (float)running * (1.0f / (float)S_TOK);
  float prod = me * ce;
#pragma unroll
  for (int off = 32; off > 0; off >>= 1) prod += __shfl_xor(prod, off, 64);
  if (e == 0) out[0] = prod * (float)NEXP;   // l_aux
}

__global__ void loc_kernel(const int* __restrict__ ind, const int* __restrict__ rnk,
                           const int* __restrict__ offs, int* __restrict__ code,
                           float* __restrict__ out)
{
  const int s = blockIdx.x * blockDim.x + threadIdx.x;
  if (s < S_TOK) {
    const int e = ind[s];
    const int loc = offs[(s / CHUNK) * NEXP + e] + rnk[s];
    code[s] = (loc < CAP) ? (e * CAP + loc) : -1;   // -1 => token dropped
    out[OFF5 + s] = (float)e;                        // indices1_s
  }
}

__device__ __forceinline__ float elem_val(int g, const int* __restrict__ code,
                                          const float* __restrict__ gval,
                                          const int* __restrict__ ind)
{
  if (g < OFF3) {                       // combine_weights or dispatch_mask
    const bool isC = g < OFF2;
    const int idx = isC ? (g - 1) : (g - OFF2);
    const int s = idx >> 13;            // / (64*128)
    const int ec = idx & 8191;          // e*128 + c
    if (code[s] != ec) return 0.0f;
    return isC ? gval[s] : 1.0f;
  } else {                              // mask1
    const int idx = g - OFF3;
    const int s = idx >> 6;
    const int e = idx & 63;
    return (ind[s] == e) ? 1.0f : 0.0f;
  }
}

__global__ __launch_bounds__(256) void write_kernel(const int* __restrict__ code,
                                                    const float* __restrict__ gval,
                                                    const int* __restrict__ ind,
                                                    float* __restrict__ out)
{
  const int total4 = (OFF4 + 3) >> 2;   // 33,685,505 float4 slots covering [0, OFF4)
  const int stride = gridDim.x * blockDim.x;
  for (int j = blockIdx.x * blockDim.x + threadIdx.x; j < total4; j += stride) {
    const int g0 = j << 2;
    if (g0 >= 4 && g0 + 4 <= OFF4) {
      float4 v;
      v.x = elem_val(g0 + 0, code, gval, ind);
      v.y = elem_val(g0 + 1, code, gval, ind);
      v.z = elem_val(g0 + 2, code, gval, ind);
      v.w = elem_val(g0 + 3, code, gval, ind);
      *reinterpret_cast<float4*>(out + g0) = v;
    } else {
      // head (g=1..3; g=0 is l_aux written by reduce_kernel) and tail
#pragma unroll
      for (int k = 0; k < 4; ++k) {
        const int g = g0 + k;
        if (g >= 1 && g < OFF4) out[g] = elem_val(g, code, gval, ind);
      }
    }
  }
}

extern "C" void kernel_launch(void* const* d_in, const int* in_sizes, int n_in,
                              void* d_out, int out_size, void* d_ws, size_t ws_size,
                              hipStream_t stream)
{
  const float* x = (const float*)d_in[0];
  const float* wg = (const float*)d_in[1];
  float* out = (float*)d_out;

  // ws layout (512 KB total)
  int* ind = (int*)d_ws;                       // 8192
  int* rnk = ind + S_TOK;                      // 8192
  float* gval = (float*)(rnk + S_TOK);         // 8192
  int* code = (int*)(gval + S_TOK);            // 8192
  int* counts = code + S_TOK;                  // 512*64
  float* gparts = (float*)(counts + NCH * NEXP);  // 512*64
  int* offs = (int*)(gparts + NCH * NEXP);     // 512*64

  gate_kernel<<<NCH, 256, 0, stream>>>(x, wg, ind, rnk, gval, counts, gparts);
  reduce_kernel<<<1, 64, 0, stream>>>(counts, gparts, offs, out);
  loc_kernel<<<(S_TOK + 255) / 256, 256, 0, stream>>>(ind, rnk, offs, code, out);
  write_kernel<<<2048, 256, 0, stream>>>(code, gval, ind, out);
}